// Round 1
// baseline (2338.531 us; speedup 1.0000x reference)
//
#include <hip/hip_runtime.h>
#include <stdint.h>

typedef short bf8_t __attribute__((ext_vector_type(8)));
typedef float f4_t __attribute__((ext_vector_type(4)));

__device__ __forceinline__ float bf2f(unsigned short u) {
  union { unsigned u; float f; } v; v.u = ((unsigned)u) << 16; return v.f;
}
__device__ __forceinline__ unsigned short f2bf(float f) {
  union { float f; unsigned u; } v; v.f = f;
  return (unsigned short)((v.u + 0x7FFFu + ((v.u >> 16) & 1u)) >> 16);
}
__device__ __forceinline__ unsigned pack2(float a, float b) {
  return (unsigned)f2bf(a) | ((unsigned)f2bf(b) << 16);
}
__device__ __forceinline__ float softplusf(float x) {
  return fmaxf(x, 0.f) + log1pf(__expf(-fabsf(x)));
}
__device__ __forceinline__ float sigmoidf(float x) {
  return 1.f / (1.f + __expf(-x));
}

// ---- index dtype sniffing: int64 vs int32 (JAX may or may not honor int64) ----
__global__ void k_flag(const unsigned* __restrict__ src, const unsigned* __restrict__ dst,
                       int* __restrict__ flag) {
  int t = threadIdx.x; // 64 threads
  unsigned hs = src[2 * t + 1] | dst[2 * t + 1];
  unsigned long long m = __ballot(hs == 0u);
  if (t == 0) *flag = (m == ~0ULL) ? 1 : 0;
}

__global__ __launch_bounds__(256) void k_convert(const unsigned* __restrict__ src,
                                                 const unsigned* __restrict__ dst,
                                                 const int* __restrict__ flag,
                                                 int* __restrict__ s32, int* __restrict__ d32,
                                                 int E) {
  int e = blockIdx.x * 256 + threadIdx.x;
  if (e >= E) return;
  bool is64 = (*flag != 0);
  s32[e] = (int)(is64 ? src[2 * e] : src[e]);
  d32[e] = (int)(is64 ? dst[2 * e] : dst[e]);
}

__global__ __launch_bounds__(256) void k_wcvt(const float* __restrict__ w,
                                              unsigned short* __restrict__ wb) {
  int i = blockIdx.x * 256 + threadIdx.x; // 32768
  wb[i] = f2bf(w[i]);
}

__global__ __launch_bounds__(256) void k_hist(const int* __restrict__ d32, int* __restrict__ cnt,
                                              int E) {
  int e = blockIdx.x * 256 + threadIdx.x;
  if (e < E) atomicAdd(&cnt[d32[e]], 1);
}

__global__ __launch_bounds__(1024) void k_scan(const int* __restrict__ cnt, int* __restrict__ offs,
                                               int* __restrict__ cursor, int N, int chunk) {
  __shared__ int sd[1024];
  int t = threadIdx.x;
  int lo = t * chunk, hi = min(lo + chunk, N);
  int s = 0;
  for (int i = lo; i < hi; ++i) s += cnt[i];
  sd[t] = s; __syncthreads();
  for (int off = 1; off < 1024; off <<= 1) {
    int v = (t >= off) ? sd[t - off] : 0;
    __syncthreads();
    sd[t] += v;
    __syncthreads();
  }
  int base = sd[t] - s; // exclusive prefix
  for (int i = lo; i < hi; ++i) {
    offs[i] = base; cursor[i] = base;
    base += cnt[i];
  }
  if (t == 1023) offs[N] = sd[1023];
}

__global__ __launch_bounds__(256) void k_scatter(const int* __restrict__ d32,
                                                 int* __restrict__ cursor, int* __restrict__ eid,
                                                 int E) {
  int e = blockIdx.x * 256 + threadIdx.x;
  if (e >= E) return;
  int pos = atomicAdd(&cursor[d32[e]], 1);
  eid[pos] = e;
}

// ---- gather + GEMM (bf16 MFMA) + fused BN1 partial stats ----
__global__ __launch_bounds__(256, 2) void k_gemm(
    const float* __restrict__ atom, const float* __restrict__ edge,
    const unsigned short* __restrict__ wb,
    const int* __restrict__ srcI, const int* __restrict__ dstI,
    unsigned short* __restrict__ z, float* __restrict__ ps) {
  __shared__ unsigned short As[128 * 264]; // 128 rows x 256 k, pad +8
  const int t = threadIdx.x;
  const int blk = blockIdx.x;
  const int row0 = blk * 128;

  // stage atom[dst] (k 0..63) and atom[src] (k 64..127)
#pragma unroll
  for (int i = 0; i < 16; ++i) {
    int f = t + 256 * i;
    int r = f >> 5, c4 = f & 31;
    int idx = (c4 < 16) ? dstI[row0 + r] : srcI[row0 + r];
    const float4 v = ((const float4*)(atom + (size_t)idx * 64))[c4 & 15];
    uint2 o; o.x = pack2(v.x, v.y); o.y = pack2(v.z, v.w);
    *(uint2*)&As[r * 264 + c4 * 4] = o;
  }
  // stage edge_fea (k 128..255), fully coalesced
#pragma unroll
  for (int i = 0; i < 16; ++i) {
    int f = t + 256 * i;
    int r = f >> 5, c4 = f & 31;
    const float4 v = ((const float4*)(edge + (size_t)(row0 + r) * 128))[c4];
    uint2 o; o.x = pack2(v.x, v.y); o.y = pack2(v.z, v.w);
    *(uint2*)&As[r * 264 + 128 + c4 * 4] = o;
  }
  __syncthreads();

  const int l = t & 63, w = t >> 6;
  const int wm = w >> 1, wn = w & 1;
  const int lrow = l & 15, quad = l >> 4;

  f4_t acc[4][4];
#pragma unroll
  for (int mt = 0; mt < 4; ++mt)
#pragma unroll
    for (int nt = 0; nt < 4; ++nt)
      acc[mt][nt] = f4_t{0.f, 0.f, 0.f, 0.f};

  const unsigned short* wbp = wb + ((wn * 64 + lrow) * 256 + quad * 8);
#pragma unroll
  for (int kc = 0; kc < 8; ++kc) {
    bf8_t a[4], b[4];
#pragma unroll
    for (int mt = 0; mt < 4; ++mt)
      a[mt] = *(const bf8_t*)&As[(wm * 64 + mt * 16 + lrow) * 264 + kc * 32 + quad * 8];
#pragma unroll
    for (int nt = 0; nt < 4; ++nt)
      b[nt] = *(const bf8_t*)(wbp + nt * 16 * 256 + kc * 32);
#pragma unroll
    for (int mt = 0; mt < 4; ++mt)
#pragma unroll
      for (int nt = 0; nt < 4; ++nt)
        acc[mt][nt] = __builtin_amdgcn_mfma_f32_16x16x32_bf16(a[mt], b[nt], acc[mt][nt], 0, 0, 0);
  }
  __syncthreads(); // everyone done with As; epilogue reuses it for stats

  float s1[4] = {0.f, 0.f, 0.f, 0.f}, s2[4] = {0.f, 0.f, 0.f, 0.f};
#pragma unroll
  for (int mt = 0; mt < 4; ++mt) {
#pragma unroll
    for (int nt = 0; nt < 4; ++nt) {
      const int col = wn * 64 + nt * 16 + lrow;
#pragma unroll
      for (int r = 0; r < 4; ++r) {
        float v = acc[mt][nt][r];
        int e = row0 + wm * 64 + mt * 16 + quad * 4 + r;
        z[(size_t)e * 128 + col] = f2bf(v);
        s1[nt] += v; s2[nt] += v * v;
      }
    }
  }
#pragma unroll
  for (int nt = 0; nt < 4; ++nt) {
    s1[nt] += __shfl_xor(s1[nt], 16); s1[nt] += __shfl_xor(s1[nt], 32);
    s2[nt] += __shfl_xor(s2[nt], 16); s2[nt] += __shfl_xor(s2[nt], 32);
  }
  float* st = (float*)As; // 2*2*128 floats
  if (quad == 0) {
#pragma unroll
    for (int nt = 0; nt < 4; ++nt) {
      const int col = wn * 64 + nt * 16 + lrow;
      st[wm * 256 + col] = s1[nt];
      st[wm * 256 + 128 + col] = s2[nt];
    }
  }
  __syncthreads();
  // ps[blk][0..127]=sum, [128..255]=sumsq
  ps[(size_t)blk * 256 + t] = st[t] + st[256 + t];
}

__global__ __launch_bounds__(256) void k_red(const float* __restrict__ ps, float* __restrict__ S,
                                             int nrows, int rowlen) {
  int bb = blockIdx.x, t = threadIdx.x;
  float a = 0.f;
  for (int b = t; b < nrows; b += 256) a += ps[(size_t)b * rowlen + bb];
  __shared__ float sd[256];
  sd[t] = a; __syncthreads();
  for (int off = 128; off > 0; off >>= 1) {
    if (t < off) sd[t] += sd[t + off];
    __syncthreads();
  }
  if (t == 0) S[bb] = sd[0];
}

__global__ void k_bnfin(const float* __restrict__ S, const float* __restrict__ w,
                        const float* __restrict__ b, float* __restrict__ ss, float invM, int H) {
  int c = threadIdx.x;
  if (c < H) {
    float mean = S[c] * invM;
    float var = S[H + c] * invM - mean * mean;
    float sc = w[c] * rsqrtf(var + 1e-5f);
    ss[c] = sc;
    ss[H + c] = b[c] - mean * sc;
  }
}

__global__ __launch_bounds__(256) void k_apply(const unsigned short* __restrict__ z,
                                               const float* __restrict__ ss,
                                               unsigned short* __restrict__ msg) {
  int gid = blockIdx.x * 256 + threadIdx.x;
  int e = gid >> 4, q = gid & 15;
  const unsigned short* zr = z + (size_t)e * 128 + q * 4;
  uint2 g = *(const uint2*)zr;
  uint2 c = *(const uint2*)(zr + 64);
  float gv[4] = {bf2f((unsigned short)(g.x & 0xffff)), bf2f((unsigned short)(g.x >> 16)),
                 bf2f((unsigned short)(g.y & 0xffff)), bf2f((unsigned short)(g.y >> 16))};
  float cv[4] = {bf2f((unsigned short)(c.x & 0xffff)), bf2f((unsigned short)(c.x >> 16)),
                 bf2f((unsigned short)(c.y & 0xffff)), bf2f((unsigned short)(c.y >> 16))};
  float m[4];
#pragma unroll
  for (int i = 0; i < 4; ++i) {
    int j = q * 4 + i;
    float gg = gv[i] * ss[j] + ss[128 + j];
    float cc = cv[i] * ss[64 + j] + ss[192 + j];
    m[i] = sigmoidf(gg) * softplusf(cc);
  }
  uint2 o; o.x = pack2(m[0], m[1]); o.y = pack2(m[2], m[3]);
  *(uint2*)(msg + (size_t)e * 64 + q * 4) = o;
}

// one wave per node, lane = feature column; CSR gather of message rows
__global__ __launch_bounds__(256) void k_aggr(const int* __restrict__ offs,
                                              const int* __restrict__ eid,
                                              const unsigned short* __restrict__ msg,
                                              float* __restrict__ aggr, float* __restrict__ pw,
                                              int N) {
  int lane = threadIdx.x & 63;
  int gw = blockIdx.x * 4 + (threadIdx.x >> 6); // 4096 waves
  float s1 = 0.f, s2 = 0.f;
  for (int n = gw; n < N; n += 4096) {
    int start = offs[n], end = offs[n + 1];
    float acc = 0.f;
    for (int i0 = start; i0 < end; i0 += 64) {
      int m = end - i0; if (m > 64) m = 64;
      int e = (lane < m) ? eid[i0 + lane] : 0;
      for (int j = 0; j < m; ++j) {
        int ej = __shfl(e, j);
        acc += bf2f(msg[(size_t)ej * 64 + lane]);
      }
    }
    aggr[(size_t)n * 64 + lane] = acc;
    s1 += acc; s2 += acc * acc;
  }
  pw[(size_t)gw * 128 + lane] = s1;
  pw[(size_t)gw * 128 + 64 + lane] = s2;
}

__global__ __launch_bounds__(256) void k_final(const float* __restrict__ atom,
                                               const float* __restrict__ aggr,
                                               const float* __restrict__ ss2,
                                               float* __restrict__ out) {
  int gid = blockIdx.x * 256 + threadIdx.x;
  int n = gid >> 4, q = gid & 15, j = q * 4;
  float4 a = *(const float4*)(atom + (size_t)n * 64 + j);
  float4 g = *(const float4*)(aggr + (size_t)n * 64 + j);
  float4 o;
  o.x = softplusf(a.x + g.x * ss2[j] + ss2[64 + j]);
  o.y = softplusf(a.y + g.y * ss2[j + 1] + ss2[64 + j + 1]);
  o.z = softplusf(a.z + g.z * ss2[j + 2] + ss2[64 + j + 2]);
  o.w = softplusf(a.w + g.w * ss2[j + 3] + ss2[64 + j + 3]);
  *(float4*)(out + (size_t)n * 64 + j) = o;
}

extern "C" void kernel_launch(void* const* d_in, const int* in_sizes, int n_in,
                              void* d_out, int out_size, void* d_ws, size_t ws_size,
                              hipStream_t stream) {
  const float* atom = (const float*)d_in[0];
  const float* edge = (const float*)d_in[1];
  const float* fcw  = (const float*)d_in[2];
  // d_in[3] = fc_b: mathematically cancelled by BN1 mean-subtraction
  const float* bn1w = (const float*)d_in[4];
  const float* bn1b = (const float*)d_in[5];
  const float* bn2w = (const float*)d_in[6];
  const float* bn2b = (const float*)d_in[7];
  const void* srcRaw = d_in[8];
  const void* dstRaw = d_in[9];

  const int N = in_sizes[0] / 64;   // 100000
  const int E = in_sizes[1] / 128;  // 1600000
  float* out = (float*)d_out;

  char* p = (char*)d_ws;
  auto alloc = [&](size_t bytes) -> void* {
    void* r = (void*)p;
    p += (bytes + 255) & ~(size_t)255;
    return r;
  };
  unsigned short* z   = (unsigned short*)alloc((size_t)E * 128 * 2);
  unsigned short* msg = (unsigned short*)alloc((size_t)E * 64 * 2);
  float* aggr   = (float*)alloc((size_t)N * 64 * 4);
  float* ps     = (float*)alloc((size_t)(E / 128) * 256 * 4);
  float* pw     = (float*)alloc((size_t)4096 * 128 * 4);
  float* S1     = (float*)alloc(256 * 4);
  float* ssA    = (float*)alloc(256 * 4);
  float* S2     = (float*)alloc(128 * 4);
  float* ss2    = (float*)alloc(128 * 4);
  int* cnt      = (int*)alloc((size_t)(N + 1) * 4);
  int* offs     = (int*)alloc((size_t)(N + 1) * 4);
  int* cursor   = (int*)alloc((size_t)(N + 1) * 4);
  int* eid      = (int*)alloc((size_t)E * 4);
  int* src32    = (int*)alloc((size_t)E * 4);
  int* dst32    = (int*)alloc((size_t)E * 4);
  int* flag     = (int*)alloc(4);
  unsigned short* wbf = (unsigned short*)alloc(128 * 256 * 2);

  k_flag<<<1, 64, 0, stream>>>((const unsigned*)srcRaw, (const unsigned*)dstRaw, flag);
  k_convert<<<(E + 255) / 256, 256, 0, stream>>>((const unsigned*)srcRaw, (const unsigned*)dstRaw,
                                                 flag, src32, dst32, E);
  hipMemsetAsync(cnt, 0, (size_t)(N + 1) * 4, stream);
  k_wcvt<<<(128 * 256) / 256, 256, 0, stream>>>(fcw, wbf);
  k_hist<<<(E + 255) / 256, 256, 0, stream>>>(dst32, cnt, E);
  k_scan<<<1, 1024, 0, stream>>>(cnt, offs, cursor, N, (N + 1023) / 1024);
  k_scatter<<<(E + 255) / 256, 256, 0, stream>>>(dst32, cursor, eid, E);
  k_gemm<<<E / 128, 256, 0, stream>>>(atom, edge, wbf, src32, dst32, z, ps);
  k_red<<<256, 256, 0, stream>>>(ps, S1, E / 128, 256);
  k_bnfin<<<1, 128, 0, stream>>>(S1, bn1w, bn1b, ssA, 1.0f / (float)E, 128);
  k_apply<<<E / 16, 256, 0, stream>>>(z, ssA, msg);
  k_aggr<<<1024, 256, 0, stream>>>(offs, eid, msg, aggr, pw, N);
  k_red<<<128, 256, 0, stream>>>(pw, S2, 4096, 128);
  k_bnfin<<<1, 64, 0, stream>>>(S2, bn2w, bn2b, ss2, 1.0f / (float)N, 64);
  k_final<<<N / 16, 256, 0, stream>>>(atom, aggr, ss2, out);
}